// Round 5
// baseline (67.159 us; speedup 1.0000x reference)
//
#include <hip/hip_runtime.h>

// W_MUL = sqrt(2)/sqrt(5)
#define WMUL 0.63245553203367586640f

typedef float v2f __attribute__((ext_vector_type(2)));   // (re, im)
typedef float v4f __attribute__((ext_vector_type(4)));   // two cplx

__device__ __forceinline__ v4f cat(v2f a, v2f b) { return __builtin_shufflevector(a, b, 0, 1, 2, 3); }
__device__ __forceinline__ v2f lo2(v4f t) { return __builtin_shufflevector(t, t, 0, 1); }
__device__ __forceinline__ v2f hi2(v4f t) { return __builtin_shufflevector(t, t, 2, 3); }

// ---- cold-path C complex math ----
__device__ __forceinline__ v2f cmul_c(v2f a, v2f b) {
    v2f r = { a.x*b.x - a.y*b.y, a.x*b.y + a.y*b.x };
    return r;
}
__device__ __forceinline__ v2f cmacc_c(v2f acc, v2f a, v2f b) {
    acc.x += a.x*b.x - a.y*b.y;
    acc.y += a.x*b.y + a.y*b.x;
    return acc;
}

// ---- hot-path packed complex MACs ----
// d += a*b (full complex, 2 instrs)
__device__ __forceinline__ void cmacc_pk(v2f& d, v2f a, v2f b) {
    asm("v_pk_fma_f32 %0, %1, %2, %0 op_sel_hi:[0,1,1]\n\t"
        "v_pk_fma_f32 %0, %1, %2, %0 op_sel:[1,1,0] op_sel_hi:[1,0,1] neg_lo:[1,0,0]"
        : "+v"(d) : "v"(a), "v"(b));
}
// d += conj(a)*b
__device__ __forceinline__ void cmacc_cj_pk(v2f& d, v2f a, v2f b) {
    asm("v_pk_fma_f32 %0, %1, %2, %0 op_sel_hi:[0,1,1]\n\t"
        "v_pk_fma_f32 %0, %1, %2, %0 op_sel:[1,1,0] op_sel_hi:[1,0,1] neg_hi:[1,0,0]"
        : "+v"(d) : "v"(a), "v"(b));
}
// d += conj(a)*m, m real duplicated in both halves
__device__ __forceinline__ void cmacc_rj_pk(v2f& d, v2f a, v2f m) {
    asm("v_pk_fma_f32 %0, %1, %2, %0 neg_hi:[1,0,0]"
        : "+v"(d) : "v"(a), "v"(m));
}
// d += a*m (a complex, m real dup) — plain packed fma
__device__ __forceinline__ void cmacc_r_pk(v2f& d, v2f a, v2f m) {
    asm("v_pk_fma_f32 %0, %1, %2, %0"
        : "+v"(d) : "v"(a), "v"(m));
}

// 256 threads, per-thread 2x2 tile (rows {2i0,2i0+1}, cols {2j0,2j0+1}).
// LDS arena (v2f units, 58.9 KB):
//   CLA  [0   ..1023]  [k*32+j] = conj(LA[j][k])
//   CLB  [1024..2047]
//   CL2A [2048..3071]
//   TAT  [3072..4159]  [j*34+i] = TA[i][j]   (pad 34)
//   W    [4160..5247]  [k*34+c] = (MB @ LB^H)[k][c]  (pad 34)
//   A1p  [5248..6303]  [r*33+c] (pad 33; head aliases gates[60])
//   Paux [6304..7359]  P2 temps P/R/Q; later ent[128]; (old B1p slot)
//   Sarr aliases [3072..3079] (TAT dead after P4)
//   Np   aliases [0..1087]    (CLA/CLB dead after P5a)
//   TFT  aliases [3072..4159] (Sarr dead after P5b)
__global__ __launch_bounds__(256)
void qmutual_kernel(const float* __restrict__ A, const float* __restrict__ B,
                    const float* __restrict__ weight, float* __restrict__ out,
                    int out_size)
{
    __shared__ __align__(16) v2f arena[7360];
    v2f* CLA   = arena;
    v2f* CLB   = arena + 1024;
    v2f* CL2A  = arena + 2048;
    v2f* TAT   = arena + 3072;
    v2f* W     = arena + 4160;
    v2f* A1p   = arena + 5248;
    v2f* Sarr  = arena + 3072;
    v2f* Np    = arena;
    v2f* TFT   = arena + 3072;
    v2f* gates = arena + 5248;   // 15 gates x 4 = 60 cplx, dead after P2
    v2f* Pb    = arena + 6304;   // 3 x 16  (G0(x)G1)
    v2f* Rb    = arena + 6352;   // 3 x 16  (G2(x)G3)
    v2f* Qb    = arena + 6400;   // 3 x 64  (G2(x)G3(x)G4)
    v2f* ent   = arena + 6304;   // 128 B1 Gray entries (reuse after P2)

    const int tid = threadIdx.x;
    const int i0 = tid >> 4, j0 = tid & 15;
    const int r0 = 2*i0, c0 = 2*j0;
    const int blk = blockIdx.x;
    const float* MA = blk ? B : A;   // block 0: A(x)B path, block 1: B(x)A path
    const float* MB = blk ? A : B;

    // ---- P1: combined per-qubit gates G = Rz*Ry*Rx (only the 15 needed) ----
    // gates[0..4]=LA factors (layer0 q0-4), [5..9]=LB (layer0 q5-9), [10..14]=L2A (layer1 q0-4)
    if (tid < 15) {
        const int layer = tid / 10, q = tid % 10;
        const float w0 = weight[6*q + 3*layer + 0] * WMUL;
        const float w1 = weight[6*q + 3*layer + 1] * WMUL;
        const float w2 = weight[6*q + 3*layer + 2] * WMUL;
        const float cx = cosf(0.5f*w0), sx = sinf(0.5f*w0);
        const float cy = cosf(0.5f*w1), sy = sinf(0.5f*w1);
        const float cz = cosf(0.5f*w2), sz = sinf(0.5f*w2);
        v2f rx[2][2] = { { {cx,0.f}, {0.f,-sx} }, { {0.f,-sx}, {cx,0.f} } };
        v2f ry[2][2] = { { {cy,0.f}, {-sy,0.f} }, { {sy,0.f}, {cy,0.f} } };
        const v2f rz0 = {cz, -sz}, rz1 = {cz, sz};
        v2f m[2][2];
        #pragma unroll
        for (int r = 0; r < 2; ++r)
            #pragma unroll
            for (int c = 0; c < 2; ++c)
                m[r][c] = cmacc_c(cmul_c(ry[r][0], rx[0][c]), ry[r][1], rx[1][c]);
        v2f* g = gates + tid*4;
        g[0] = cmul_c(rz0, m[0][0]); g[1] = cmul_c(rz0, m[0][1]);
        g[2] = cmul_c(rz1, m[1][0]); g[3] = cmul_c(rz1, m[1][1]);
    }
    __syncthreads();

    // ---- P2a: pair-krons P = G0(x)G1, R = G2(x)G3 (1 cmul/thread) ----
    if (tid < 48) {
        const int m = tid >> 4, idx = tid & 15;
        const int jh = idx >> 2, kh = idx & 3;
        Pb[m*16 + idx] = cmul_c(gates[(5*m+0)*4 + (jh>>1)*2 + (kh>>1)],
                                gates[(5*m+1)*4 + (jh&1)*2 + (kh&1)]);
    } else if (tid < 96) {
        const int t = tid - 48, m = t >> 4, idx = t & 15;
        const int jm = idx >> 2, km = idx & 3;
        Rb[m*16 + idx] = cmul_c(gates[(5*m+2)*4 + (jm>>1)*2 + (km>>1)],
                                gates[(5*m+3)*4 + (jm&1)*2 + (km&1)]);
    }
    __syncthreads();

    // ---- P2b: Q = R(x)G4 (8x8, 1 cmul/thread) ----
    if (tid < 192) {
        const int m = tid >> 6, idx = tid & 63;
        const int jl = idx >> 3, kl = idx & 7;
        Qb[m*64 + idx] = cmul_c(Rb[m*16 + (jl>>1)*4 + (kl>>1)],
                                gates[(5*m+4)*4 + (jl&1)*2 + (kl&1)]);
    }
    __syncthreads();

    // ---- P2c: CLA/CLB/CL2A[k*32+j] = conj(P[j>>3][k>>3] * Q[j&7][k&7]) ----
    {
        const int jh = c0 >> 3, kh = r0 >> 3, jl0 = c0 & 7, kl0 = r0 & 7;
        v2f* dst[3] = { CLA, CLB, CL2A };
        #pragma unroll
        for (int m = 0; m < 3; ++m) {
            const v2f Pv = Pb[m*16 + jh*4 + kh];
            const v4f q0 = *(const v4f*)&Qb[m*64 + jl0*8 + kl0];       // (jl0,kl0..kl0+1)
            const v4f q1 = *(const v4f*)&Qb[m*64 + (jl0+1)*8 + kl0];
            const v2f v00 = cmul_c(Pv, lo2(q0));   // k=r0  , j=c0
            const v2f v10 = cmul_c(Pv, hi2(q0));   // k=r0+1, j=c0
            const v2f v01 = cmul_c(Pv, lo2(q1));   // k=r0  , j=c0+1
            const v2f v11 = cmul_c(Pv, hi2(q1));   // k=r0+1, j=c0+1
            const v2f n00 = {v00.x, -v00.y}, n01 = {v01.x, -v01.y};
            const v2f n10 = {v10.x, -v10.y}, n11 = {v11.x, -v11.y};
            *(v4f*)&dst[m][(r0  )*32 + c0] = cat(n00, n01);
            *(v4f*)&dst[m][(r0+1)*32 + c0] = cat(n10, n11);
        }
    }
    __syncthreads();

    // ---- P3: TA = LA @ MA   and   W = MB @ LB^H  (merged loop) ----
    {
        v2f ta[2][2] = {}, w[2][2] = {};
        #pragma unroll
        for (int k = 0; k < 32; ++k) {
            const v4f xa = *(const v4f*)&CLA[k*32 + r0];   // conj(LA[r0/r1][k])
            const float2 ma = *(const float2*)&MA[k*32 + c0];
            const v4f cb = *(const v4f*)&CLB[k*32 + c0];   // conj(LB[c0/c1][k])
            const float mb0 = MB[r0*32 + k], mb1 = MB[(r0+1)*32 + k];
            const v2f xa0 = lo2(xa), xa1 = hi2(xa);
            const v2f cb0 = lo2(cb), cb1 = hi2(cb);
            const v2f mx = {ma.x, ma.x}, my = {ma.y, ma.y};
            const v2f m0 = {mb0, mb0},  m1 = {mb1, mb1};
            // TA[r][c] += conj(CLA[k][r]) * MA[k][c]
            cmacc_rj_pk(ta[0][0], xa0, mx); cmacc_rj_pk(ta[0][1], xa0, my);
            cmacc_rj_pk(ta[1][0], xa1, mx); cmacc_rj_pk(ta[1][1], xa1, my);
            // W[r][c] += MB[r][k] * conj(LB[c][k])  (= MB @ LB^H)
            cmacc_r_pk(w[0][0], cb0, m0); cmacc_r_pk(w[0][1], cb1, m0);
            cmacc_r_pk(w[1][0], cb0, m1); cmacc_r_pk(w[1][1], cb1, m1);
        }
        #pragma unroll
        for (int g = 0; g < 2; ++g)
            *(v4f*)&TAT[(c0+g)*34 + r0] = cat(ta[0][g], ta[1][g]);
        #pragma unroll
        for (int p = 0; p < 2; ++p)
            *(v4f*)&W[(r0+p)*34 + c0] = cat(w[p][0], w[p][1]);
    }
    __syncthreads();

    // ---- P4: A1 = TA @ LA^H  +  128 Gray entries of B1 = LB @ W ----
    {
        v2f a1[2][2] = {};
        #pragma unroll
        for (int k = 0; k < 32; ++k) {
            const v4f t  = *(const v4f*)&TAT[k*34 + r0];   // TA[r0/r1][k]
            const v4f ca = *(const v4f*)&CLA[k*32 + c0];   // conj(LA[c0/c1][k])
            const v2f t0 = lo2(t), t1 = hi2(t);
            const v2f ca0 = lo2(ca), ca1 = hi2(ca);
            cmacc_pk(a1[0][0], t0, ca0); cmacc_pk(a1[0][1], t0, ca1);
            cmacc_pk(a1[1][0], t1, ca0); cmacc_pk(a1[1][1], t1, ca1);
        }
        #pragma unroll
        for (int p = 0; p < 2; ++p)
            #pragma unroll
            for (int g = 0; g < 2; ++g)
                A1p[(r0+p)*33 + c0+g] = a1[p][g];

        // B1[r][c] = sum_k conj(CLB[k*32+r]) * W[k][c], only at Gray positions.
        // 2 threads per entry (k-halves), shfl_xor(1) pair reduction.
        const int e = tid >> 1, h = tid & 1;
        const int kb = e >> 2, eps = (e >> 1) & 1, del = e & 1;
        const int gg = kb ^ (kb >> 1);
        const int rB = (eps << 4) ^ gg, cB = (del << 4) ^ gg;
        v2f acc = {0.f, 0.f};
        #pragma unroll
        for (int i = 0; i < 16; ++i) {
            const int k = 16*h + i;
            cmacc_cj_pk(acc, CLB[k*32 + rB], W[k*34 + cB]);
        }
        acc.x += __shfl_xor(acc.x, 1);
        acc.y += __shfl_xor(acc.y, 1);
        if (h == 0) ent[e] = acc;
    }
    __syncthreads();

    // ---- P5a: S[p][eps][del] = sum_{kb==p mod 2} ent[kb*4 + eps*2 + del] ----
    if (tid < 8) {
        const int p = (tid >> 2) & 1, eps = (tid >> 1) & 1, del = tid & 1;
        v2f s = {0.f, 0.f};
        #pragma unroll
        for (int m = 0; m < 16; ++m)
            s += ent[(2*m + p)*4 + eps*2 + del];
        Sarr[tid] = s;   // TAT head, dead after P4
    }
    __syncthreads();

    // ---- P5b: N[r,c] = A1[G(r)][G(c)]*S[0][r&1][c&1] + A1[G(r)^24][G(c)^24]*S[1][..]
    {
        const int gr0 = r0 ^ (r0 >> 1), gr1 = (r0+1) ^ ((r0+1) >> 1);
        const int gc0 = c0 ^ (c0 >> 1), gc1 = (c0+1) ^ ((c0+1) >> 1);
        const v2f A00 = A1p[gr0*33 + gc0],           A01 = A1p[gr0*33 + gc1];
        const v2f A10 = A1p[gr1*33 + gc0],           A11 = A1p[gr1*33 + gc1];
        const v2f X00 = A1p[(gr0^24)*33 + (gc0^24)], X01 = A1p[(gr0^24)*33 + (gc1^24)];
        const v2f X10 = A1p[(gr1^24)*33 + (gc0^24)], X11 = A1p[(gr1^24)*33 + (gc1^24)];
        v2f n[2][2] = {};
        cmacc_pk(n[0][0], A00, Sarr[0]); cmacc_pk(n[0][0], X00, Sarr[4]);
        cmacc_pk(n[0][1], A01, Sarr[1]); cmacc_pk(n[0][1], X01, Sarr[5]);
        cmacc_pk(n[1][0], A10, Sarr[2]); cmacc_pk(n[1][0], X10, Sarr[6]);
        cmacc_pk(n[1][1], A11, Sarr[3]); cmacc_pk(n[1][1], X11, Sarr[7]);
        #pragma unroll
        for (int p = 0; p < 2; ++p)
            *(v4f*)&Np[(r0+p)*34 + c0] = cat(n[p][0], n[p][1]);   // CLA/CLB dead
    }
    __syncthreads();

    // ---- P6: TF = L2A @ N  (L2A[i][k] = conj(CL2A[k*32+i])) ----
    {
        v2f tf[2][2] = {};
        #pragma unroll
        for (int k = 0; k < 32; ++k) {
            const v4f x = *(const v4f*)&CL2A[k*32 + r0];
            const v4f m = *(const v4f*)&Np[k*34 + c0];
            const v2f x0 = lo2(x), x1 = hi2(x), m0 = lo2(m), m1 = hi2(m);
            cmacc_cj_pk(tf[0][0], x0, m0); cmacc_cj_pk(tf[0][1], x0, m1);
            cmacc_cj_pk(tf[1][0], x1, m0); cmacc_cj_pk(tf[1][1], x1, m1);
        }
        __syncthreads();   // Np reads done; TFT overwrites Sarr region
        #pragma unroll
        for (int g = 0; g < 2; ++g)
            *(v4f*)&TFT[(c0+g)*34 + r0] = cat(tf[0][g], tf[1][g]);
    }
    __syncthreads();

    // ---- P7: R = TF @ L2A^H, store ----
    {
        v2f rr[2][2] = {};
        #pragma unroll
        for (int k = 0; k < 32; ++k) {
            const v4f t  = *(const v4f*)&TFT[k*34 + r0];
            const v4f c2 = *(const v4f*)&CL2A[k*32 + c0];
            const v2f t0 = lo2(t), t1 = hi2(t), c20 = lo2(c2), c21 = hi2(c2);
            cmacc_pk(rr[0][0], t0, c20); cmacc_pk(rr[0][1], t0, c21);
            cmacc_pk(rr[1][0], t1, c20); cmacc_pk(rr[1][1], t1, c21);
        }
        if (out_size >= 4096) {
            #pragma unroll
            for (int p = 0; p < 2; ++p)
                *(v4f*)&out[blk*2048 + (r0+p)*64 + 4*j0] = cat(rr[p][0], rr[p][1]);
        } else {
            #pragma unroll
            for (int p = 0; p < 2; ++p) {
                float2 v = { rr[p][0].x, rr[p][1].x };
                *(float2*)&out[blk*1024 + (r0+p)*32 + c0] = v;
            }
        }
    }
}

extern "C" void kernel_launch(void* const* d_in, const int* in_sizes, int n_in,
                              void* d_out, int out_size, void* d_ws, size_t ws_size,
                              hipStream_t stream) {
    const float* A = (const float*)d_in[0];   // inputA 32x32 fp32
    const float* B = (const float*)d_in[1];   // inputB 32x32 fp32
    const float* w = (const float*)d_in[2];   // weight 60 fp32
    float* out = (float*)d_out;
    qmutual_kernel<<<2, 256, 0, stream>>>(A, B, w, out, out_size);
}